// Round 1
// baseline (203.719 us; speedup 1.0000x reference)
//
#include <hip/hip_runtime.h>
#include <math.h>

#define HF 64
#define WF 64
#define CC 512
#define NROI 256
#define NBINS 21   // 1 + 4 + 16

// fine bins: acc[ix][iy], ix = x-bin (W axis), iy = y-bin (H axis)
// output bins: [0]=p1, [1+i2*2+j2]=p2, [5+ix*4+iy]=p4
__global__ __launch_bounds__(256) void roi_pool_kernel(
    const float* __restrict__ img,
    const float* __restrict__ rois,
    float* __restrict__ out)
{
    const int roi = blockIdx.x;
    const int tid = threadIdx.x;
    const int c0  = tid * 2;            // 256 threads x 2 ch = 512 ch

    const float x = rois[roi * 4 + 0];
    const float y = rois[roi * 4 + 1];
    const float w = rois[roi * 4 + 2];
    const float h = rois[roi * 4 + 3];

    // p=4 boundaries; exact fp32 two-step (mul then add), round-half-even.
    // NOTE: x-boundaries use h (col_len = h/p), y-boundaries use w — reference quirk.
    const float clh = h * 0.25f;   // exact
    const float clw = w * 0.25f;   // exact
    int bx[5], by[5];
#pragma unroll
    for (int i = 0; i < 5; ++i) {
        bx[i] = (int)rintf(__fadd_rn(x, __fmul_rn((float)i, clh)));
        by[i] = (int)rintf(__fadd_rn(y, __fmul_rn((float)i, clw)));
    }

    float2 acc[4][4];
#pragma unroll
    for (int i = 0; i < 4; ++i)
#pragma unroll
        for (int j = 0; j < 4; ++j) {
            acc[i][j].x = -INFINITY;
            acc[i][j].y = -INFINITY;
        }

    const float* base = img + c0;

#pragma unroll
    for (int jy = 0; jy < 4; ++jy) {
        for (int hh = by[jy]; hh < by[jy + 1]; ++hh) {
            const float* rowp = base + (size_t)hh * (WF * CC);
#pragma unroll
            for (int jx = 0; jx < 4; ++jx) {
                for (int ww = bx[jx]; ww < bx[jx + 1]; ++ww) {
                    const float2 v = *(const float2*)(rowp + (size_t)ww * CC);
                    acc[jx][jy].x = fmaxf(acc[jx][jy].x, v.x);
                    acc[jx][jy].y = fmaxf(acc[jx][jy].y, v.y);
                }
            }
        }
    }

    float* outr = out + (size_t)roi * (NBINS * CC) + c0;

    // p=4: bins 5 + ix*4 + iy
#pragma unroll
    for (int ix = 0; ix < 4; ++ix)
#pragma unroll
        for (int iy = 0; iy < 4; ++iy) {
            *(float2*)(outr + (size_t)(5 + ix * 4 + iy) * CC) = acc[ix][iy];
        }

    // p=2: bins 1 + i2*2 + j2 = max over fine {2i2,2i2+1} x {2j2,2j2+1}
    float2 q[2][2];
#pragma unroll
    for (int i2 = 0; i2 < 2; ++i2)
#pragma unroll
        for (int j2 = 0; j2 < 2; ++j2) {
            float2 v;
            v.x = fmaxf(fmaxf(acc[2*i2][2*j2].x, acc[2*i2+1][2*j2].x),
                        fmaxf(acc[2*i2][2*j2+1].x, acc[2*i2+1][2*j2+1].x));
            v.y = fmaxf(fmaxf(acc[2*i2][2*j2].y, acc[2*i2+1][2*j2].y),
                        fmaxf(acc[2*i2][2*j2+1].y, acc[2*i2+1][2*j2+1].y));
            q[i2][j2] = v;
            *(float2*)(outr + (size_t)(1 + i2 * 2 + j2) * CC) = v;
        }

    // p=1: bin 0 = max over everything
    float2 g;
    g.x = fmaxf(fmaxf(q[0][0].x, q[0][1].x), fmaxf(q[1][0].x, q[1][1].x));
    g.y = fmaxf(fmaxf(q[0][0].y, q[0][1].y), fmaxf(q[1][0].y, q[1][1].y));
    *(float2*)(outr) = g;
}

extern "C" void kernel_launch(void* const* d_in, const int* in_sizes, int n_in,
                              void* d_out, int out_size, void* d_ws, size_t ws_size,
                              hipStream_t stream) {
    const float* img  = (const float*)d_in[0];   // (1,64,64,512) fp32
    const float* rois = (const float*)d_in[1];   // (1,256,4) fp32
    float* out = (float*)d_out;                  // (1,256,21*512) fp32

    dim3 grid(NROI);
    dim3 block(256);
    roi_pool_kernel<<<grid, block, 0, stream>>>(img, rois, out);
}

// Round 2
// 36.767 us; speedup vs baseline: 5.5408x; 5.5408x over previous
//
#include <hip/hip_runtime.h>
#include <math.h>

#define HF 64
#define WF 64
#define CC 512
#define NROI 256
#define NBINS 21   // 1 + 4 + 16

// Kernel A: one block per (roi, jy, jx) fine bin; 256 threads x float2 = 512 ch.
// Writes p4 output bins [5 + jx*4 + jy].
__global__ __launch_bounds__(256) void roi_pool_fine(
    const float* __restrict__ img,
    const float* __restrict__ rois,
    float* __restrict__ out)
{
    const int roi = blockIdx.x;
    const int jy  = blockIdx.y;   // y fine-bin (H axis)
    const int jx  = blockIdx.z;   // x fine-bin (W axis)
    const int c0  = threadIdx.x * 2;

    const float x = rois[roi * 4 + 0];
    const float y = rois[roi * 4 + 1];
    const float w = rois[roi * 4 + 2];
    const float h = rois[roi * 4 + 3];

    // Reference quirk: x-boundaries (W axis) use col_len = h/p; y-boundaries use w/p.
    const float clh = h * 0.25f;   // exact
    const float clw = w * 0.25f;   // exact

    const int x1 = (int)rintf(__fadd_rn(x, __fmul_rn((float)jx,        clh)));
    const int x2 = (int)rintf(__fadd_rn(x, __fmul_rn((float)(jx + 1),  clh)));
    const int y1 = (int)rintf(__fadd_rn(y, __fmul_rn((float)jy,        clw)));
    const int y2 = (int)rintf(__fadd_rn(y, __fmul_rn((float)(jy + 1),  clw)));

    float2 acc;
    acc.x = -INFINITY;
    acc.y = -INFINITY;

    const float* base = img + c0;
    for (int hh = y1; hh < y2; ++hh) {
        const float* rowp = base + (size_t)hh * (WF * CC);
        for (int ww = x1; ww < x2; ++ww) {
            const float2 v = *(const float2*)(rowp + (size_t)ww * CC);
            acc.x = fmaxf(acc.x, v.x);
            acc.y = fmaxf(acc.y, v.y);
        }
    }

    float* outr = out + (size_t)roi * (NBINS * CC) + c0;
    *(float2*)(outr + (size_t)(5 + jx * 4 + jy) * CC) = acc;
}

// Kernel B: one block per roi; reads the 16 p4 bins, writes p2 (bins 1..4) and p1 (bin 0).
__global__ __launch_bounds__(256) void roi_pool_coarse(
    float* __restrict__ out)
{
    const int roi = blockIdx.x;
    const int c0  = threadIdx.x * 2;

    float* outr = out + (size_t)roi * (NBINS * CC) + c0;

    float2 fine[4][4];   // [ix][iy]
#pragma unroll
    for (int ix = 0; ix < 4; ++ix)
#pragma unroll
        for (int iy = 0; iy < 4; ++iy)
            fine[ix][iy] = *(const float2*)(outr + (size_t)(5 + ix * 4 + iy) * CC);

    float2 q[2][2];
#pragma unroll
    for (int i2 = 0; i2 < 2; ++i2)
#pragma unroll
        for (int j2 = 0; j2 < 2; ++j2) {
            float2 v;
            v.x = fmaxf(fmaxf(fine[2*i2][2*j2].x, fine[2*i2+1][2*j2].x),
                        fmaxf(fine[2*i2][2*j2+1].x, fine[2*i2+1][2*j2+1].x));
            v.y = fmaxf(fmaxf(fine[2*i2][2*j2].y, fine[2*i2+1][2*j2].y),
                        fmaxf(fine[2*i2][2*j2+1].y, fine[2*i2+1][2*j2+1].y));
            q[i2][j2] = v;
            *(float2*)(outr + (size_t)(1 + i2 * 2 + j2) * CC) = v;
        }

    float2 g;
    g.x = fmaxf(fmaxf(q[0][0].x, q[0][1].x), fmaxf(q[1][0].x, q[1][1].x));
    g.y = fmaxf(fmaxf(q[0][0].y, q[0][1].y), fmaxf(q[1][0].y, q[1][1].y));
    *(float2*)(outr) = g;
}

extern "C" void kernel_launch(void* const* d_in, const int* in_sizes, int n_in,
                              void* d_out, int out_size, void* d_ws, size_t ws_size,
                              hipStream_t stream) {
    const float* img  = (const float*)d_in[0];   // (1,64,64,512) fp32
    const float* rois = (const float*)d_in[1];   // (1,256,4) fp32
    float* out = (float*)d_out;                  // (1,256,21*512) fp32

    dim3 gridA(NROI, 4, 4);
    dim3 block(256);
    roi_pool_fine<<<gridA, block, 0, stream>>>(img, rois, out);

    dim3 gridB(NROI);
    roi_pool_coarse<<<gridB, block, 0, stream>>>(out);
}

// Round 3
// 25.424 us; speedup vs baseline: 8.0129x; 1.4462x over previous
//
#include <hip/hip_runtime.h>
#include <math.h>

#define HF 64
#define WF 64
#define CC 512
#define NROI 256
#define NBINS 21   // 1 + 4 + 16

// Channel-quarter sharding: C=512 split into 4 quarters of 128 ch.
// Quarter q is routed to XCD pair {2q, 2q+1} via blockIdx swizzle (xcd = bid & 7
// round-robin heuristic). Per-XCD read working set = 64*64*128*4B = 2 MB < 4 MiB L2.

// Kernel A: one block (64 thr) per (roi, fine-bin, quarter). Writes p4 bins.
__global__ __launch_bounds__(64) void roi_pool_fine(
    const float* __restrict__ img,
    const float* __restrict__ rois,
    float* __restrict__ out)
{
    const int bid = blockIdx.x;            // [0, 16384)
    const int x7  = bid & 7;               // target XCD (heuristic)
    const int q   = x7 >> 1;               // channel quarter 0..3
    const int wu  = ((bid >> 3) << 1) | (bid & 1);   // [0, 4096) bijective
    const int roi = wu >> 4;
    const int bin = wu & 15;
    const int jx  = bin >> 2;              // x fine-bin (W axis)
    const int jy  = bin & 3;               // y fine-bin (H axis)
    const int c0  = q * 128 + threadIdx.x * 2;

    const float x = rois[roi * 4 + 0];
    const float y = rois[roi * 4 + 1];
    const float w = rois[roi * 4 + 2];
    const float h = rois[roi * 4 + 3];

    // Reference quirk: x-boundaries (W axis) use col_len = h/p; y-boundaries use w/p.
    const float clh = h * 0.25f;   // exact
    const float clw = w * 0.25f;   // exact

    const int x1 = (int)rintf(__fadd_rn(x, __fmul_rn((float)jx,       clh)));
    const int x2 = (int)rintf(__fadd_rn(x, __fmul_rn((float)(jx + 1), clh)));
    const int y1 = (int)rintf(__fadd_rn(y, __fmul_rn((float)jy,       clw)));
    const int y2 = (int)rintf(__fadd_rn(y, __fmul_rn((float)(jy + 1), clw)));

    float2 acc;
    acc.x = -INFINITY;
    acc.y = -INFINITY;

    const float* base = img + c0;
    for (int hh = y1; hh < y2; ++hh) {
        const float* rowp = base + (size_t)hh * (WF * CC);
        for (int ww = x1; ww < x2; ++ww) {
            const float2 v = *(const float2*)(rowp + (size_t)ww * CC);
            acc.x = fmaxf(acc.x, v.x);
            acc.y = fmaxf(acc.y, v.y);
        }
    }

    float* outr = out + (size_t)roi * (NBINS * CC) + c0;
    *(float2*)(outr + (size_t)(5 + jx * 4 + jy) * CC) = acc;
}

// Kernel B: one block (64 thr) per (roi, quarter); reads the 16 p4 bins,
// writes p2 (bins 1..4) and p1 (bin 0). Same quarter->XCD swizzle.
__global__ __launch_bounds__(64) void roi_pool_coarse(
    float* __restrict__ out)
{
    const int bid = blockIdx.x;            // [0, 1024)
    const int x7  = bid & 7;
    const int q   = x7 >> 1;
    const int roi = ((bid >> 3) << 1) | (bid & 1);   // [0, 256)
    const int c0  = q * 128 + threadIdx.x * 2;

    float* outr = out + (size_t)roi * (NBINS * CC) + c0;

    float2 fine[4][4];   // [ix][iy]
#pragma unroll
    for (int ix = 0; ix < 4; ++ix)
#pragma unroll
        for (int iy = 0; iy < 4; ++iy)
            fine[ix][iy] = *(const float2*)(outr + (size_t)(5 + ix * 4 + iy) * CC);

    float2 qv[2][2];
#pragma unroll
    for (int i2 = 0; i2 < 2; ++i2)
#pragma unroll
        for (int j2 = 0; j2 < 2; ++j2) {
            float2 v;
            v.x = fmaxf(fmaxf(fine[2*i2][2*j2].x, fine[2*i2+1][2*j2].x),
                        fmaxf(fine[2*i2][2*j2+1].x, fine[2*i2+1][2*j2+1].x));
            v.y = fmaxf(fmaxf(fine[2*i2][2*j2].y, fine[2*i2+1][2*j2].y),
                        fmaxf(fine[2*i2][2*j2+1].y, fine[2*i2+1][2*j2+1].y));
            qv[i2][j2] = v;
            *(float2*)(outr + (size_t)(1 + i2 * 2 + j2) * CC) = v;
        }

    float2 g;
    g.x = fmaxf(fmaxf(qv[0][0].x, qv[0][1].x), fmaxf(qv[1][0].x, qv[1][1].x));
    g.y = fmaxf(fmaxf(qv[0][0].y, qv[0][1].y), fmaxf(qv[1][0].y, qv[1][1].y));
    *(float2*)(outr) = g;
}

extern "C" void kernel_launch(void* const* d_in, const int* in_sizes, int n_in,
                              void* d_out, int out_size, void* d_ws, size_t ws_size,
                              hipStream_t stream) {
    const float* img  = (const float*)d_in[0];   // (1,64,64,512) fp32
    const float* rois = (const float*)d_in[1];   // (1,256,4) fp32
    float* out = (float*)d_out;                  // (1,256,21*512) fp32

    dim3 gridA(NROI * 16 * 4);   // 16384 blocks
    dim3 blockA(64);
    roi_pool_fine<<<gridA, blockA, 0, stream>>>(img, rois, out);

    dim3 gridB(NROI * 4);        // 1024 blocks
    roi_pool_coarse<<<gridB, blockA, 0, stream>>>(out);
}

// Round 4
// 22.288 us; speedup vs baseline: 9.1402x; 1.1407x over previous
//
#include <hip/hip_runtime.h>
#include <math.h>

#define HF 64
#define WF 64
#define CC 512
#define NROI 256
#define NBINS 21   // 1 + 4 + 16

__device__ __forceinline__ float4 max4(float4 a, float4 b) {
    float4 r;
    r.x = fmaxf(a.x, b.x); r.y = fmaxf(a.y, b.y);
    r.z = fmaxf(a.z, b.z); r.w = fmaxf(a.w, b.w);
    return r;
}

// Kernel A: block = (roi, quarter, jy), 256 threads (4 waves).
// Wave w handles fine bin (jx=w, jy). Lanes 0-31: even pixel-columns,
// lanes 32-63: odd pixel-columns; float4 over the 128-ch quarter.
// XCD swizzle: bid&7 -> XCD, quarter q = (bid&7)>>1 so quarter q lands on
// XCD pair {2q,2q+1}; per-XCD image working set = 64*64*128*4B = 2 MB < 4 MiB L2.
__global__ __launch_bounds__(256) void roi_pool_fine(
    const float* __restrict__ img,
    const float* __restrict__ rois,
    float* __restrict__ out)
{
    const int bid  = blockIdx.x;                    // [0, 4096)
    const int x7   = bid & 7;
    const int q    = x7 >> 1;                       // channel quarter
    const int rest = ((bid >> 3) << 1) | (bid & 1); // [0, 1024) bijective
    const int roi  = rest >> 2;
    const int jy   = rest & 3;                      // y fine-bin (H axis)
    const int tid  = threadIdx.x;
    const int jx   = tid >> 6;                      // wave id = x fine-bin (W axis)
    const int lane = tid & 63;
    const int half = lane >> 5;                     // pixel parity
    const int cl   = lane & 31;
    const int c0   = q * 128 + cl * 4;

    const float x = rois[roi * 4 + 0];
    const float y = rois[roi * 4 + 1];
    const float w = rois[roi * 4 + 2];
    const float h = rois[roi * 4 + 3];

    // Reference quirk: x-boundaries (W axis) use col_len = h/p; y-boundaries use w/p.
    const float clh = h * 0.25f;   // exact
    const float clw = w * 0.25f;   // exact

    const int x1 = (int)rintf(__fadd_rn(x, __fmul_rn((float)jx,       clh)));
    const int x2 = (int)rintf(__fadd_rn(x, __fmul_rn((float)(jx + 1), clh)));
    const int y1 = (int)rintf(__fadd_rn(y, __fmul_rn((float)jy,       clw)));
    const int y2 = (int)rintf(__fadd_rn(y, __fmul_rn((float)(jy + 1), clw)));

    float4 acc;
    acc.x = -INFINITY; acc.y = -INFINITY; acc.z = -INFINITY; acc.w = -INFINITY;

    const float* base = img + c0;
    for (int hh = y1; hh < y2; ++hh) {
        const float* rowp = base + (size_t)hh * (WF * CC);
        for (int ww0 = x1; ww0 < x2; ww0 += 2) {
            const int ww = ww0 + half;
            if (ww < x2) {
                const float4 v = *(const float4*)(rowp + (size_t)ww * CC);
                acc = max4(acc, v);
            }
        }
    }

    // combine the two pixel-parity halves (same channels, disjoint pixel sets)
    acc.x = fmaxf(acc.x, __shfl_xor(acc.x, 32));
    acc.y = fmaxf(acc.y, __shfl_xor(acc.y, 32));
    acc.z = fmaxf(acc.z, __shfl_xor(acc.z, 32));
    acc.w = fmaxf(acc.w, __shfl_xor(acc.w, 32));

    if (half == 0) {
        float* outr = out + (size_t)roi * (NBINS * CC) + c0;
        *(float4*)(outr + (size_t)(5 + jx * 4 + jy) * CC) = acc;
    }
}

// Kernel B: block = (roi, quarter), 64 threads. Lane half h2 = i2 handles
// fine columns ix in {2*h2, 2*h2+1}; float4 over the 128-ch quarter.
// Writes p2 bins [1 + h2*2 + j2]; p1 via cross-half shfl combine.
__global__ __launch_bounds__(64) void roi_pool_coarse(
    float* __restrict__ out)
{
    const int bid  = blockIdx.x;                    // [0, 1024)
    const int q    = (bid & 7) >> 1;
    const int roi  = ((bid >> 3) << 1) | (bid & 1); // [0, 256)
    const int lane = threadIdx.x;
    const int h2   = lane >> 5;                     // i2 (x-coarse bin)
    const int cl   = lane & 31;
    const int c0   = q * 128 + cl * 4;

    float* outr = out + (size_t)roi * (NBINS * CC) + c0;

    float4 f[2][4];   // [a][iy], ix = 2*h2 + a
#pragma unroll
    for (int a = 0; a < 2; ++a)
#pragma unroll
        for (int iy = 0; iy < 4; ++iy)
            f[a][iy] = *(const float4*)(outr + (size_t)(5 + (2 * h2 + a) * 4 + iy) * CC);

    float4 p2v[2];
#pragma unroll
    for (int j2 = 0; j2 < 2; ++j2) {
        float4 v = max4(max4(f[0][2 * j2], f[0][2 * j2 + 1]),
                        max4(f[1][2 * j2], f[1][2 * j2 + 1]));
        *(float4*)(outr + (size_t)(1 + h2 * 2 + j2) * CC) = v;
        p2v[j2] = v;
    }

    float4 m = max4(p2v[0], p2v[1]);
    m.x = fmaxf(m.x, __shfl_xor(m.x, 32));
    m.y = fmaxf(m.y, __shfl_xor(m.y, 32));
    m.z = fmaxf(m.z, __shfl_xor(m.z, 32));
    m.w = fmaxf(m.w, __shfl_xor(m.w, 32));
    if (h2 == 0) {
        *(float4*)(outr) = m;
    }
}

extern "C" void kernel_launch(void* const* d_in, const int* in_sizes, int n_in,
                              void* d_out, int out_size, void* d_ws, size_t ws_size,
                              hipStream_t stream) {
    const float* img  = (const float*)d_in[0];   // (1,64,64,512) fp32
    const float* rois = (const float*)d_in[1];   // (1,256,4) fp32
    float* out = (float*)d_out;                  // (1,256,21*512) fp32

    dim3 gridA(NROI * 4 * 4);    // (roi, quarter, jy) = 4096 blocks
    dim3 blockA(256);
    roi_pool_fine<<<gridA, blockA, 0, stream>>>(img, rois, out);

    dim3 gridB(NROI * 4);        // (roi, quarter) = 1024 blocks
    dim3 blockB(64);
    roi_pool_coarse<<<gridB, blockB, 0, stream>>>(out);
}